// Round 2
// baseline (103.981 us; speedup 1.0000x reference)
//
#include <hip/hip_runtime.h>

// VolumetricRayMarcher: B=4, R=65536, S=128. One 64-lane wave per ray.
// out[ray][c] = sum_s alpha_s * T_s * rgb[s][c],
//   T_s = prod_{j<s}(1-alpha_j+1e-10), alpha_s = 1-exp(-density_s*delta_s),
//   delta_s = 1.9/127 (s<127), 1e10 (s=127).
//
// Coalescing plan (all loads perfectly contiguous per wave):
//   density: float2/lane  (512 B/wave)
//   rgb:     float4/lane (floats 4i..4i+3) + float2/lane (floats 256+2i..)
// The cumprod scan produces w[2i],w[2i+1] on lane i; weights are scattered to
// a per-wave LDS array so each lane can gather w[f/3] for its rgb floats
// (the final sum is order-free, so lanes need not own "their" samples' rgb).

#define NSAMP 128
typedef float f32x4 __attribute__((ext_vector_type(4)));
typedef float f32x2 __attribute__((ext_vector_type(2)));

__global__ __launch_bounds__(256) void VolumetricRayMarcher_kernel(
    const float* __restrict__ rgb,      // [n_rays, 128, 3]
    const float* __restrict__ density,  // [n_rays, 128]
    float* __restrict__ out,            // [n_rays, 3]
    int n_rays) {
    __shared__ float w_lds[4][NSAMP];   // per-wave sample weights
    __shared__ float o_lds[12];         // per-block staged outputs (4 rays x 3)

    const int lane = threadIdx.x & 63;
    const int wave = threadIdx.x >> 6;
    int ray = blockIdx.x * 4 + wave;
    const bool valid = (ray < n_rays);
    if (!valid) ray = n_rays - 1;       // clamp so loads stay in bounds

    const float DELTA = (2.0f - 0.1f) / (float)(NSAMP - 1);  // 1.9/127

    // ---- coalesced streaming loads (rgb issued early, overlaps the scan) ----
    const f32x2 dpair = __builtin_nontemporal_load(
        (const f32x2*)(density + (size_t)ray * NSAMP) + lane);
    const float* rbase = rgb + (size_t)ray * (NSAMP * 3);
    const f32x4 v4 = __builtin_nontemporal_load((const f32x4*)rbase + lane);        // floats 4i..4i+3
    const f32x2 v2 = __builtin_nontemporal_load((const f32x2*)rbase + 128 + lane);  // floats 256+2i..

    // ---- alpha / factors for samples 2i, 2i+1 ----
    const float delta1 = (lane == 63) ? 1e10f : DELTA;
    const float alpha0 = 1.0f - __expf(-dpair[0] * DELTA);
    const float alpha1 = 1.0f - __expf(-dpair[1] * delta1);
    const float f0 = 1.0f - alpha0 + 1e-10f;
    const float f1 = 1.0f - alpha1 + 1e-10f;

    // ---- exclusive cumprod: inclusive scan of per-lane pair products ----
    float p = f0 * f1;
    #pragma unroll
    for (int off = 1; off < 64; off <<= 1) {
        float o = __shfl_up(p, off, 64);
        if (lane >= off) p *= o;
    }
    float excl = __shfl_up(p, 1, 64);   // product of all factors before sample 2i
    if (lane == 0) excl = 1.0f;

    const float w0 = alpha0 * excl;          // weight of sample 2i
    const float w1 = alpha1 * excl * f0;     // weight of sample 2i+1

    // scatter weights to this wave's LDS slice (ds_write_b64, 2-way = free)
    ((f32x2*)w_lds[wave])[lane] = f32x2{w0, w1};

    // ---- accumulate: each lane handles 6 contiguous rgb floats ----
    float acc0 = 0.f, acc1 = 0.f, acc2 = 0.f;
    #pragma unroll
    for (int k = 0; k < 4; ++k) {
        const int f = 4 * lane + k;          // float index within ray
        const int s = f / 3;                 // sample
        const int c = f - 3 * s;             // channel
        const float t = w_lds[wave][s] * v4[k];
        acc0 += (c == 0) ? t : 0.0f;
        acc1 += (c == 1) ? t : 0.0f;
        acc2 += (c == 2) ? t : 0.0f;
    }
    #pragma unroll
    for (int k = 0; k < 2; ++k) {
        const int f = 256 + 2 * lane + k;
        const int s = f / 3;
        const int c = f - 3 * s;
        const float t = w_lds[wave][s] * v2[k];
        acc0 += (c == 0) ? t : 0.0f;
        acc1 += (c == 1) ? t : 0.0f;
        acc2 += (c == 2) ? t : 0.0f;
    }

    // ---- wave butterfly reduce (3 channels) ----
    #pragma unroll
    for (int off = 32; off > 0; off >>= 1) {
        acc0 += __shfl_xor(acc0, off, 64);
        acc1 += __shfl_xor(acc1, off, 64);
        acc2 += __shfl_xor(acc2, off, 64);
    }

    if (lane == 0) {
        o_lds[wave * 3 + 0] = acc0;
        o_lds[wave * 3 + 1] = acc1;
        o_lds[wave * 3 + 2] = acc2;
    }
    __syncthreads();

    // ---- coalesced 48 B output store per block ----
    const int t = threadIdx.x;
    if (t < 12) {
        const int oray = blockIdx.x * 4 + t / 3;
        if (oray < n_rays)
            __builtin_nontemporal_store(o_lds[t], out + (size_t)blockIdx.x * 12 + t);
    }
}

extern "C" void kernel_launch(void* const* d_in, const int* in_sizes, int n_in,
                              void* d_out, int out_size, void* d_ws, size_t ws_size,
                              hipStream_t stream) {
    const float* rgb     = (const float*)d_in[0];   // [B,R,S,3] f32
    const float* density = (const float*)d_in[1];   // [B,R,S]   f32
    float* out = (float*)d_out;                     // [B,R,3]   f32

    const int n_rays = in_sizes[1] / NSAMP;         // B*R = 262144
    const int blocks = (n_rays + 3) / 4;            // 4 waves (rays) per block

    hipLaunchKernelGGL(VolumetricRayMarcher_kernel, dim3(blocks), dim3(256), 0, stream,
                       rgb, density, out, n_rays);
}

// Round 3
// 101.391 us; speedup vs baseline: 1.0255x; 1.0255x over previous
//
#include <hip/hip_runtime.h>

// VolumetricRayMarcher: B=4, R=65536, S=128. One 64-lane wave per ray.
// out[ray][c] = sum_s alpha_s * T_s * rgb[s][c],
//   T_s = prod_{j<s}(1-alpha_j+1e-10), alpha_s = 1-exp(-density_s*delta_s),
//   delta_s = 1.9/127 (s<127), 1e10 (s=127).
//
// R3: fully-coalesced rgb loads (float4 + float2 per lane), weights
// redistributed through a per-wave LDS slice (NO barrier — only the owning
// wave touches its slice), channel assignment via 3-way rotation (cheap),
// direct 12 B store from lane 0 (as R1). Isolates the rgb load pattern.

#define NSAMP 128
typedef float f32x4 __attribute__((ext_vector_type(4)));
typedef float f32x2 __attribute__((ext_vector_type(2)));

__global__ __launch_bounds__(256) void VolumetricRayMarcher_kernel(
    const float* __restrict__ rgb,      // [n_rays, 128, 3]
    const float* __restrict__ density,  // [n_rays, 128]
    float* __restrict__ out,            // [n_rays, 3]
    int n_rays) {
    __shared__ float w_lds[4][NSAMP + 2];  // +2 pad: s+1 gather can touch idx 128

    const int lane = threadIdx.x & 63;
    const int wave = threadIdx.x >> 6;
    const int ray  = blockIdx.x * 4 + wave;
    if (ray >= n_rays) return;

    const float DELTA = 1.9f / 127.0f;

    // ---- all global loads issued up front, fully coalesced per wave ----
    const f32x2 dpair = ((const f32x2*)(density + (size_t)ray * NSAMP))[lane];
    const float* rbase = rgb + (size_t)ray * (NSAMP * 3);
    const f32x4 v4 = ((const f32x4*)rbase)[lane];        // floats 4i .. 4i+3
    const f32x2 v2 = ((const f32x2*)rbase)[128 + lane];  // floats 256+2i, 257+2i

    // ---- alpha / transmittance factors for samples 2i, 2i+1 ----
    const float delta1 = (lane == 63) ? 1e10f : DELTA;
    const float alpha0 = 1.0f - __expf(-dpair[0] * DELTA);
    const float alpha1 = 1.0f - __expf(-dpair[1] * delta1);
    const float f0 = 1.0f - alpha0 + 1e-10f;
    const float f1 = 1.0f - alpha1 + 1e-10f;

    // ---- exclusive cumprod: wave scan over per-lane pair products ----
    float p = f0 * f1;
    #pragma unroll
    for (int off = 1; off < 64; off <<= 1) {
        float o = __shfl_up(p, off, 64);
        if (lane >= off) p *= o;
    }
    float excl = __shfl_up(p, 1, 64);
    if (lane == 0) excl = 1.0f;

    const float w0 = alpha0 * excl;       // weight of sample 2i
    const float w1 = alpha1 * excl * f0;  // weight of sample 2i+1

    // per-wave weight scatter (row base 520 B -> 8B-aligned f32x2 store)
    ((f32x2*)w_lds[wave])[lane] = f32x2{w0, w1};

    // ---- v4 part: floats 4i..4i+3 span samples s0,s0+1; channels rotate by r=i%3 ----
    const int s0 = (4 * lane) / 3;
    const int r  = lane % 3;              // == (4*lane) % 3
    const float wA = w_lds[wave][s0];
    const float wB = w_lds[wave][s0 + 1];
    const float t0 = wA * v4[0];
    const float t1 = ((r == 2) ? wB : wA) * v4[1];
    const float t2 = ((r == 0) ? wA : wB) * v4[2];
    const float t3 = wB * v4[3];
    const float u0 = t0 + t3, u1 = t1, u2 = t2;  // u_j belongs to channel (r+j)%3
    float acc0 = (r == 0) ? u0 : (r == 1) ? u2 : u1;
    float acc1 = (r == 0) ? u1 : (r == 1) ? u0 : u2;
    float acc2 = (r == 0) ? u2 : (r == 1) ? u1 : u0;

    // ---- v2 part: floats 256+2i, 257+2i span samples s4,s4+1; channels r2,(r2+1)%3 ----
    const int f4 = 256 + 2 * lane;
    const int s4 = f4 / 3;
    const int r2 = f4 % 3;
    const float wC = w_lds[wave][s4];
    const float wD = w_lds[wave][s4 + 1];
    const float t4 = wC * v2[0];
    const float t5 = ((r2 == 2) ? wD : wC) * v2[1];
    acc0 += (r2 == 0) ? t4 : (r2 == 2) ? t5 : 0.0f;
    acc1 += (r2 == 1) ? t4 : (r2 == 0) ? t5 : 0.0f;
    acc2 += (r2 == 2) ? t4 : (r2 == 1) ? t5 : 0.0f;

    // ---- wave butterfly reduce (3 channels) ----
    #pragma unroll
    for (int off = 32; off > 0; off >>= 1) {
        acc0 += __shfl_xor(acc0, off, 64);
        acc1 += __shfl_xor(acc1, off, 64);
        acc2 += __shfl_xor(acc2, off, 64);
    }

    if (lane == 0) {
        float* o = out + (size_t)ray * 3;
        o[0] = acc0;
        o[1] = acc1;
        o[2] = acc2;
    }
}

extern "C" void kernel_launch(void* const* d_in, const int* in_sizes, int n_in,
                              void* d_out, int out_size, void* d_ws, size_t ws_size,
                              hipStream_t stream) {
    const float* rgb     = (const float*)d_in[0];   // [B,R,S,3] f32
    const float* density = (const float*)d_in[1];   // [B,R,S]   f32
    float* out = (float*)d_out;                     // [B,R,3]   f32

    const int n_rays = in_sizes[1] / NSAMP;         // B*R = 262144
    const int blocks = (n_rays + 3) / 4;            // 4 waves (rays) per block

    hipLaunchKernelGGL(VolumetricRayMarcher_kernel, dim3(blocks), dim3(256), 0, stream,
                       rgb, density, out, n_rays);
}

// Round 4
// 95.275 us; speedup vs baseline: 1.0914x; 1.0642x over previous
//
#include <hip/hip_runtime.h>

// VolumetricRayMarcher: B=4, R=65536, S=128.
// R4: 2 rays per 64-lane wave (32 lanes/ray), 4 samples per lane.
//   out[ray][c] = sum_s alpha_s * T_s * rgb[s][c]
//   T_s = prod_{j<s}(1-alpha_j+1e-10), alpha_s = 1-exp(-density_s*delta_s)
//   delta_s = 1.9/127 (s<127), 1e10 (s=127).
//
// Per lane: samples 4l..4l+3 of its half-wave's ray.
//   density: one f32x4 load (wave touches 1 KB contiguous: 2 adjacent rays)
//   rgb:     three f32x4 loads = floats 12l..12l+11 (exactly 4 samples x RGB,
//            static channel map since 12 % 3 == 0 — no per-lane rotation)
// Scan: 5-step width-32 __shfl_up inclusive scan of per-lane 4-factor products,
// shifted to exclusive; 5-step width-32 butterfly reduce x3 channels.
// No LDS, no barriers; both rays share one instruction stream.

#define NSAMP 128
typedef float f32x4 __attribute__((ext_vector_type(4)));

__global__ __launch_bounds__(256) void VolumetricRayMarcher_kernel(
    const float* __restrict__ rgb,      // [n_rays, 128, 3]
    const float* __restrict__ density,  // [n_rays, 128]
    float* __restrict__ out,            // [n_rays, 3]
    int n_rays) {
    const int lane = threadIdx.x & 63;
    const int h    = lane >> 5;          // which ray of the wave's pair
    const int l    = lane & 31;          // lane within the 32-lane half
    const int wave = threadIdx.x >> 6;
    const int ray  = blockIdx.x * 8 + wave * 2 + h;
    if (ray >= n_rays) return;

    const float DELTA = 1.9f / 127.0f;

    // ---- loads issued up front ----
    const f32x4 d4 = ((const f32x4*)(density + (size_t)ray * NSAMP))[l];
    const f32x4* rg = (const f32x4*)(rgb + (size_t)ray * (NSAMP * 3)) + (size_t)l * 3;
    const f32x4 a = rg[0];   // s0.r s0.g s0.b s1.r
    const f32x4 b = rg[1];   // s1.g s1.b s2.r s2.g
    const f32x4 c = rg[2];   // s2.b s3.r s3.g s3.b

    // ---- alphas / factors for samples 4l..4l+3 ----
    const float dl3 = (l == 31) ? 1e10f : DELTA;   // sample 127 gets 1e10
    const float al0 = 1.0f - __expf(-d4.x * DELTA);
    const float al1 = 1.0f - __expf(-d4.y * DELTA);
    const float al2 = 1.0f - __expf(-d4.z * DELTA);
    const float al3 = 1.0f - __expf(-d4.w * dl3);
    const float f0 = 1.0f - al0 + 1e-10f;
    const float f1 = 1.0f - al1 + 1e-10f;
    const float f2 = 1.0f - al2 + 1e-10f;
    const float f3 = 1.0f - al3 + 1e-10f;

    // ---- exclusive cumprod: width-32 scan of per-lane products ----
    float p = (f0 * f1) * (f2 * f3);
    #pragma unroll
    for (int off = 1; off < 32; off <<= 1) {
        float o = __shfl_up(p, off, 32);
        if (l >= off) p *= o;
    }
    float excl = __shfl_up(p, 1, 32);   // product of all factors before sample 4l
    if (l == 0) excl = 1.0f;

    float t = excl;
    const float w0 = al0 * t; t *= f0;
    const float w1 = al1 * t; t *= f1;
    const float w2 = al2 * t; t *= f2;
    const float w3 = al3 * t;

    // ---- weighted rgb, static channel mapping ----
    float acc0 = w0 * a.x + w1 * a.w + w2 * b.z + w3 * c.y;
    float acc1 = w0 * a.y + w1 * b.x + w2 * b.w + w3 * c.z;
    float acc2 = w0 * a.z + w1 * b.y + w2 * c.x + w3 * c.w;

    // ---- width-32 butterfly reduce (both rays in parallel) ----
    #pragma unroll
    for (int off = 16; off > 0; off >>= 1) {
        acc0 += __shfl_xor(acc0, off, 32);
        acc1 += __shfl_xor(acc1, off, 32);
        acc2 += __shfl_xor(acc2, off, 32);
    }

    if (l == 0) {
        float* o = out + (size_t)ray * 3;
        o[0] = acc0;
        o[1] = acc1;
        o[2] = acc2;
    }
}

extern "C" void kernel_launch(void* const* d_in, const int* in_sizes, int n_in,
                              void* d_out, int out_size, void* d_ws, size_t ws_size,
                              hipStream_t stream) {
    const float* rgb     = (const float*)d_in[0];   // [B,R,S,3] f32
    const float* density = (const float*)d_in[1];   // [B,R,S]   f32
    float* out = (float*)d_out;                     // [B,R,3]   f32

    const int n_rays = in_sizes[1] / NSAMP;         // B*R = 262144
    const int blocks = (n_rays + 7) / 8;            // 8 rays per 256-thread block

    hipLaunchKernelGGL(VolumetricRayMarcher_kernel, dim3(blocks), dim3(256), 0, stream,
                       rgb, density, out, n_rays);
}